// Round 2
// baseline (3409.419 us; speedup 1.0000x reference)
//
#include <hip/hip_runtime.h>

#define E_EDGES 320000
#define N_NODES 10000
#define F_DIM   128
#define C_DIM   384      // 3*F
#define NRBF_K  20
#define TILE    32       // edges per block-tile
#define TP      36       // padded LDS row stride (floats): 144B = 16B-aligned
#define PI_F    3.14159265358979323846f

// ---------------------------------------------------------------- sum(r^2) over all E*3
__global__ void sumsq_kernel(const float* __restrict__ r,
                             float* __restrict__ out) {
    __shared__ float red[4];
    int tid = blockIdx.x * blockDim.x + threadIdx.x;
    int stride = gridDim.x * blockDim.x;
    float acc = 0.f;
    for (int i = tid; i < E_EDGES * 3; i += stride) {
        float x = r[i];
        acc += x * x;
    }
    #pragma unroll
    for (int off = 32; off > 0; off >>= 1)
        acc += __shfl_down(acc, off, 64);
    int lane = threadIdx.x & 63;
    int wave = threadIdx.x >> 6;
    if (lane == 0) red[wave] = acc;
    __syncthreads();
    if (threadIdx.x == 0) {
        float s = red[0] + red[1] + red[2] + red[3];
        atomicAdd(out, s);
    }
}

// ---------------------------------------------------------------- main fused kernel
// 256 threads = 4 waves. Thread (lane=cl, wave=wv) owns columns
// {cl, cl+64, cl+128, cl+192, cl+256, cl+320} (b = 0..5, col = 64*b + cl)
// for edges 8*wv .. 8*wv+7.  Every global access (v loads, out_v/out_s atomics)
// is therefore a full-wave DENSE 256B segment — atomic coalescing preserved.
// Scatter goes straight from accumulators -> atomics (no split_sh exchange).
__global__ __launch_bounds__(256, 3) void main_kernel(
    const float* __restrict__ s,      // E x 128
    const float* __restrict__ r,      // E x 3
    const float* __restrict__ v,      // E x 3 x 128
    const int*   __restrict__ idx_i,  // E
    const float* __restrict__ W_phi,  // 128 x 384
    const float* __restrict__ b_phi,  // 384
    const float* __restrict__ W_w,    // 20 x 384
    const float* __restrict__ b_w,    // 384
    const float* __restrict__ sumsq,  // ws scalar: sum of r^2 (global Frobenius)
    float* __restrict__ out_v,        // N*3*128 (f32, zeroed, atomic accumulate)
    float* __restrict__ out_s)        // N*128
{
    __shared__ float s_tile[F_DIM][TP];      // [k][e]  (broadcast-read along e)
    __shared__ float rbf_sh[NRBF_K][TP];     // [n][e]
    __shared__ float orn_sh[TILE][3];
    __shared__ int   idx_sh[TILE];

    const int tid = threadIdx.x;
    const int cl  = tid & 63;        // base column; owns cols 64*b + cl
    const int wv  = tid >> 6;        // wave id -> edge group
    const int e8  = wv * 8;
    const float inv_gn = rsqrtf(*sumsq);   // 1/||r||_F (matches jnp.linalg.norm(org_r))

    float bp[6], bw[6];
    #pragma unroll
    for (int b = 0; b < 6; b++) {
        bp[b] = b_phi[64 * b + cl];
        bw[b] = b_w[64 * b + cl];
    }

    const int ntiles = E_EDGES / TILE;          // 10000 exact
    for (int t = blockIdx.x; t < ntiles; t += gridDim.x) {
        const int e0 = t * TILE;

        // ---- stage: s tile (coalesced global read, transposed LDS write) ----
        {
            const int k  = tid & 127;
            const int eb = tid >> 7;            // 0..1
            #pragma unroll
            for (int i = 0; i < 16; i++) {
                int e = eb + 2 * i;
                s_tile[k][e] = s[(size_t)(e0 + e) * F_DIM + k];
            }
        }
        // ---- stage: rbf (20 x 32) ----
        for (int q = tid; q < TILE * NRBF_K; q += 256) {
            int e = q / NRBF_K;
            int n = q - e * NRBF_K;
            float r0 = r[(e0 + e) * 3 + 0];
            float r1 = r[(e0 + e) * 3 + 1];
            float r2 = r[(e0 + e) * 3 + 2];
            float rn = sqrtf(r0 * r0 + r1 * r1 + r2 * r2);
            float arg  = (float)(n + 1) * (PI_F / 5.0f) * rn;
            float tv   = sinf(arg) / rn;
            rbf_sh[n][e] = (tv <= 5.0f) ? 0.5f * (cosf(PI_F * tv / 5.0f) + 1.0f)
                                        : 0.0f;
        }
        // ---- stage: org_rn + idx ----
        if (tid < TILE) {
            float r0 = r[(e0 + tid) * 3 + 0];
            float r1 = r[(e0 + tid) * 3 + 1];
            float r2 = r[(e0 + tid) * 3 + 2];
            orn_sh[tid][0] = r0 * inv_gn;
            orn_sh[tid][1] = r1 * inv_gn;
            orn_sh[tid][2] = r2 * inv_gn;
            idx_sh[tid] = idx_i[e0 + tid];
        }
        __syncthreads();

        // ---- register-tiled GEMMs: phi = s@W_phi + b ; w = rbf@W_w + b ----
        float ap[6][8], aw[6][8];
        #pragma unroll
        for (int b = 0; b < 6; b++)
            #pragma unroll
            for (int e = 0; e < 8; e++) { ap[b][e] = bp[b]; aw[b][e] = bw[b]; }

        #pragma unroll
        for (int n = 0; n < NRBF_K; n++) {
            float wv6[6];
            #pragma unroll
            for (int b = 0; b < 6; b++) wv6[b] = W_w[n * C_DIM + 64 * b + cl];
            float sv[8];
            *(float4*)&sv[0] = *(const float4*)&rbf_sh[n][e8];
            *(float4*)&sv[4] = *(const float4*)&rbf_sh[n][e8 + 4];
            #pragma unroll
            for (int b = 0; b < 6; b++)
                #pragma unroll
                for (int e = 0; e < 8; e++) aw[b][e] += wv6[b] * sv[e];
        }

        for (int k = 0; k < F_DIM; k++) {
            float wv6[6];
            #pragma unroll
            for (int b = 0; b < 6; b++) wv6[b] = W_phi[k * C_DIM + 64 * b + cl];
            float sv[8];
            *(float4*)&sv[0] = *(const float4*)&s_tile[k][e8];
            *(float4*)&sv[4] = *(const float4*)&s_tile[k][e8 + 4];
            #pragma unroll
            for (int b = 0; b < 6; b++)
                #pragma unroll
                for (int e = 0; e < 8; e++) ap[b][e] += wv6[b] * sv[e];
        }

        // ---- scatter straight from registers (all wave-dense) ----
        #pragma unroll
        for (int e = 0; e < 8; e++) {
            const int ee  = e8 + e;
            const int idx = idx_sh[ee];
            const size_t vb = (size_t)(e0 + ee) * C_DIM + cl;
            float o0 = orn_sh[ee][0], o1 = orn_sh[ee][1], o2 = orn_sh[ee][2];
            float* ovp = out_v + (size_t)idx * C_DIM + cl;
            float* osp = out_s + (size_t)idx * F_DIM + cl;
            // b = 0..1 : sv block (out_v d=0 uses o0)  — wait: block d = b>>1
            float sv0 = ap[0][e] * aw[0][e];   // col cl        (d0 part of sv)
            float sv1 = ap[1][e] * aw[1][e];   // col cl+64
            float ss0 = ap[2][e] * aw[2][e];   // cols 128..255 -> out_s
            float ss1 = ap[3][e] * aw[3][e];
            float sr0 = ap[4][e] * aw[4][e];   // cols 256..383 -> radial part
            float sr1 = ap[5][e] * aw[5][e];
            // v_msg[d][f] = sv[f] * v[d][f] + sr[f] * orn[d] ; f in {cl, cl+64}
            float vv;
            vv = v[vb];           atomicAdd(ovp,       sv0 * vv + sr0 * o0);
            vv = v[vb + 64];      atomicAdd(ovp + 64,  sv1 * vv + sr1 * o0);
            vv = v[vb + 128];     atomicAdd(ovp + 128, sv0 * vv + sr0 * o1);
            vv = v[vb + 192];     atomicAdd(ovp + 192, sv1 * vv + sr1 * o1);
            vv = v[vb + 256];     atomicAdd(ovp + 256, sv0 * vv + sr0 * o2);
            vv = v[vb + 320];     atomicAdd(ovp + 320, sv1 * vv + sr1 * o2);
            atomicAdd(osp,      ss0);
            atomicAdd(osp + 64, ss1);
        }
        __syncthreads();   // orn_sh/idx_sh/s_tile rewritten next iteration
    }
}

extern "C" void kernel_launch(void* const* d_in, const int* in_sizes, int n_in,
                              void* d_out, int out_size, void* d_ws, size_t ws_size,
                              hipStream_t stream) {
    const float* s     = (const float*)d_in[0];
    const float* r     = (const float*)d_in[1];
    const float* v     = (const float*)d_in[2];
    const int*   idx_i = (const int*)d_in[3];
    const float* W_phi = (const float*)d_in[4];
    const float* b_phi = (const float*)d_in[5];
    const float* W_w   = (const float*)d_in[6];
    const float* b_w   = (const float*)d_in[7];

    float* out   = (float*)d_out;               // [out_v (N*3*F)] [out_s (N*F)]
    float* sumsq = (float*)d_ws;                // one scalar (16B zeroed)
    const int NV = N_NODES * 3 * F_DIM;         // 3,840,000

    // d_out / d_ws are poisoned 0xAA before every launch — zero what we accumulate into.
    hipMemsetAsync(d_out, 0, (size_t)out_size * sizeof(float), stream);
    hipMemsetAsync(d_ws, 0, 16, stream);
    sumsq_kernel<<<512, 256, 0, stream>>>(r, sumsq);
    main_kernel<<<2500, 256, 0, stream>>>(s, r, v, idx_i, W_phi, b_phi, W_w, b_w,
                                          sumsq, out, out + NV);
}